// Round 7
// baseline (148.976 us; speedup 1.0000x reference)
//
#include <hip/hip_runtime.h>

typedef short short8 __attribute__((ext_vector_type(8)));
typedef float f32x4 __attribute__((ext_vector_type(4)));

#define NROWS 2048
#define NCOLS 100000
#define NPAD  100352              // 98 chunks * 1024
#define NCHUNK 98
#define K2C  28.853900817779268f  // 20 * log2(e)
#define PADC 7.2552607e-7f        // 352 * exp(-20): pad-column bias

__device__ __forceinline__ unsigned short f2bf(float f) {
  unsigned int u = __float_as_uint(f);
  u = u + 0x7FFFu + ((u >> 16) & 1u);   // round to nearest even
  return (unsigned short)(u >> 16);
}

// ---- normalize inputs, scale by K2C, convert to bf16; also compute picked ----
__global__ void k_prep(const float* __restrict__ X, const int* __restrict__ idx,
                       const int* __restrict__ lab, const float* __restrict__ F,
                       unsigned short* __restrict__ Abf, float* __restrict__ picked) {
  int wid = threadIdx.x >> 6, lane = threadIdx.x & 63;
  int row = blockIdx.x * 4 + wid;
  int t = lab[idx[row]];
  float2 v = ((const float2*)(X + (size_t)row * 128))[lane];
  float2 f = ((const float2*)(F + (size_t)t * 128))[lane];
  float ss = v.x * v.x + v.y * v.y;
  float dp = v.x * f.x + v.y * f.y;
#pragma unroll
  for (int m = 1; m < 64; m <<= 1) {
    ss += __shfl_xor(ss, m, 64);
    dp += __shfl_xor(dp, m, 64);
  }
  float invn = 1.0f / fmaxf(sqrtf(ss), 1e-12f);
  float s = invn * K2C;               // fold 20*log2(e) into A
  ushort2 o;
  o.x = f2bf(v.x * s);
  o.y = f2bf(v.y * s);
  ((ushort2*)(Abf + (size_t)row * 128))[lane] = o;
  if (lane == 0) picked[row] = 20.0f * dp * invn;
}

// ---- convert features f32 -> bf16, zero-pad rows [100000,100352) ----
__global__ void k_conv(const float* __restrict__ F, unsigned short* __restrict__ Fbf) {
  const int NG = NPAD * 128 / 4;     // 3,211,264 groups of 4
  const int NV = NCOLS * 128 / 4;    // 3,200,000 valid groups
  int stride = gridDim.x * blockDim.x;
  for (int g = blockIdx.x * blockDim.x + threadIdx.x; g < NG; g += stride) {
    float4 v;
    if (g < NV) v = ((const float4*)F)[g];
    else        v = make_float4(0.f, 0.f, 0.f, 0.f);
    ushort4 o;
    o.x = f2bf(v.x); o.y = f2bf(v.y); o.z = f2bf(v.z); o.w = f2bf(v.w);
    ((ushort4*)Fbf)[g] = o;
  }
}

// ---- fused GEMM + sum of exp(logit - 20), barrier-free ----
// grid = 832 = 8 xcd * 104 slots; all 8 m-tiles of a chunk share one XCD so
// the bf16 chunk is HBM-fetched once and served from L2/L1 after.
// No LDS staging: each wave streams B-fragments global->VGPR, 16 cols/step,
// 1-step software pipeline, zero barriers in the main loop.
__global__ __launch_bounds__(256, 3) void k_gemm(
    const unsigned short* __restrict__ Abf,
    const unsigned short* __restrict__ Fbf,
    float* __restrict__ part) {
  __shared__ float xpose[4][64];                  // part-store transpose only
  const int tid = threadIdx.x;
  const int wid = tid >> 6, lane = tid & 63;
  const int lrow = lane & 15, lk = lane >> 4;

  const int slot = blockIdx.x >> 3;     // [0,104)
  const int xcd  = blockIdx.x & 7;
  const int mtile = slot & 7;
  const int chunk = (slot >> 3) * 8 + xcd;
  if (chunk >= NCHUNK) return;
  const int row0 = mtile * 256 + wid * 64;

  // A fragments in registers (Abf already scaled by 20*log2e): 64 VGPR
  short8 af[4][4];
#pragma unroll
  for (int mf = 0; mf < 4; ++mf)
#pragma unroll
    for (int ks = 0; ks < 4; ++ks)
      af[mf][ks] = *(const short8*)(Abf + (size_t)(row0 + mf * 16 + lrow) * 128 + (ks * 4 + lk) * 8);

  float racc[4][4];
#pragma unroll
  for (int mf = 0; mf < 4; ++mf)
#pragma unroll
    for (int j = 0; j < 4; ++j) racc[mf][j] = 0.f;

  // per-lane base for B-fragment loads: col (chunk*1024 + lrow), k-off lk*8
  const unsigned short* fb = Fbf + ((size_t)(chunk * 1024 + lrow) * 128 + lk * 8);
  // step t covers cols [t*16, t*16+16): addr + t*16*128 elems; ks stride 32

  auto loadB = [&](int t, short8* b) {
#pragma unroll
    for (int ks = 0; ks < 4; ++ks)
      b[ks] = *(const short8*)(fb + (size_t)t * 2048 + ks * 32);
  };

  auto computeB = [&](const short8* b) {
    f32x4 acc[4];
#pragma unroll
    for (int mf = 0; mf < 4; ++mf)
      acc[mf] = (f32x4){-K2C, -K2C, -K2C, -K2C};   // fold the -20 shift
#pragma unroll
    for (int ks = 0; ks < 4; ++ks)
#pragma unroll
      for (int mf = 0; mf < 4; ++mf)
        acc[mf] = __builtin_amdgcn_mfma_f32_16x16x32_bf16(
            af[mf][ks], b[ks], acc[mf], 0, 0, 0);
    // acc holds (20*cos - 20)*log2e: one exp2 per logit
#pragma unroll
    for (int mf = 0; mf < 4; ++mf)
#pragma unroll
      for (int j = 0; j < 4; ++j)
        racc[mf][j] += __builtin_amdgcn_exp2f(acc[mf][j]);
  };

  short8 bA[4], bB[4];
  loadB(0, bA);
#pragma unroll 1
  for (int t = 0; t < 62; t += 2) {
    loadB(t + 1, bB);
    computeB(bA);          // step t
    loadB(t + 2, bA);
    computeB(bB);          // step t+1
  }
  loadB(63, bB);
  computeB(bA);            // step 62
  computeB(bB);            // step 63

  // reduce across 16 lanes per row, transpose via LDS, coalesced store
#pragma unroll
  for (int mf = 0; mf < 4; ++mf)
#pragma unroll
    for (int j = 0; j < 4; ++j) {
      float v = racc[mf][j];
      v += __shfl_xor(v, 1, 64);
      v += __shfl_xor(v, 2, 64);
      v += __shfl_xor(v, 4, 64);
      v += __shfl_xor(v, 8, 64);
      if (lrow == 0) xpose[wid][mf * 16 + lk * 4 + j] = v;
    }
  __syncthreads();
  part[(size_t)chunk * NROWS + row0 + lane] = xpose[wid][lane];
}

// ---- stage 1 reduction: 56 blocks, each sums 14 chunks for 256 rows ----
__global__ void k_loss1(const float* __restrict__ part, float* __restrict__ psum) {
  int rb = blockIdx.x & 7, cb = blockIdx.x >> 3;   // cb in [0,7)
  int b = rb * 256 + threadIdx.x;
  float s = 0.f;
#pragma unroll
  for (int k = 0; k < 14; ++k)
    s += part[(size_t)(cb * 14 + k) * NROWS + b];
  psum[(size_t)cb * NROWS + b] = s;
}

// ---- final: per-row logz - picked, mean ----
__global__ void k_final(const float* __restrict__ psum, const float* __restrict__ picked,
                        float* __restrict__ out) {
  int tid = threadIdx.x;
  float lb = 0.f;
#pragma unroll
  for (int rr = 0; rr < 2; ++rr) {
    int b = rr * 1024 + tid;
    float tot = 0.f;
#pragma unroll
    for (int cb = 0; cb < 7; ++cb) tot += psum[(size_t)cb * NROWS + b];
    tot -= PADC;                     // remove pad-column contribution
    lb += 20.0f + logf(tot) - picked[b];
  }
#pragma unroll
  for (int m = 1; m < 64; m <<= 1) lb += __shfl_xor(lb, m, 64);
  __shared__ float red[16];
  if ((tid & 63) == 0) red[tid >> 6] = lb;
  __syncthreads();
  if (tid == 0) {
    float s = 0.f;
#pragma unroll
    for (int i = 0; i < 16; ++i) s += red[i];
    out[0] = s * (1.0f / 2048.0f);
  }
}

extern "C" void kernel_launch(void* const* d_in, const int* in_sizes, int n_in,
                              void* d_out, int out_size, void* d_ws, size_t ws_size,
                              hipStream_t stream) {
  const float* inputs  = (const float*)d_in[0];
  const int*   indexes = (const int*)d_in[1];
  const int*   labels  = (const int*)d_in[2];
  const float* feats   = (const float*)d_in[3];
  float* out = (float*)d_out;

  char* ws = (char*)d_ws;
  unsigned short* Abf = (unsigned short*)(ws + 0);        // 524,288 B
  unsigned short* Fbf = (unsigned short*)(ws + 524288);   // 25,690,112 B
  float* part   = (float*)(ws + 26214400);                // 98*2048*4 = 802,816
  float* psum   = (float*)(ws + 27017216);                // 7*2048*4  = 57,344
  float* picked = (float*)(ws + 27074560);                // 2048*4

  hipLaunchKernelGGL(k_prep,  dim3(512),  dim3(256),  0, stream, inputs, indexes, labels, feats, Abf, picked);
  hipLaunchKernelGGL(k_conv,  dim3(2048), dim3(256),  0, stream, feats, Fbf);
  hipLaunchKernelGGL(k_gemm,  dim3(832),  dim3(256),  0, stream, Abf, Fbf, part);
  hipLaunchKernelGGL(k_loss1, dim3(56),   dim3(256),  0, stream, part, psum);
  hipLaunchKernelGGL(k_final, dim3(1),    dim3(1024), 0, stream, psum, picked, out);
}

// Round 8
// 93.643 us; speedup vs baseline: 1.5909x; 1.5909x over previous
//
#include <hip/hip_runtime.h>

typedef short short8 __attribute__((ext_vector_type(8)));
typedef float f32x4 __attribute__((ext_vector_type(4)));

#define AS1 __attribute__((address_space(1)))
#define AS3 __attribute__((address_space(3)))

#define NROWS 2048
#define NCOLS 100000
#define NPAD  100352              // 98 chunks * 1024
#define NCHUNK 98
#define K2C  28.853900817779268f  // 20 * log2(e)
#define PADC 7.2552607e-7f        // 352 * exp(-20): pad-column bias

__device__ __forceinline__ unsigned short f2bf(float f) {
  unsigned int u = __float_as_uint(f);
  u = u + 0x7FFFu + ((u >> 16) & 1u);   // round to nearest even
  return (unsigned short)(u >> 16);
}

// ---- normalize inputs, scale by K2C, convert to bf16; also compute picked ----
__global__ void k_prep(const float* __restrict__ X, const int* __restrict__ idx,
                       const int* __restrict__ lab, const float* __restrict__ F,
                       unsigned short* __restrict__ Abf, float* __restrict__ picked) {
  int wid = threadIdx.x >> 6, lane = threadIdx.x & 63;
  int row = blockIdx.x * 4 + wid;
  int t = lab[idx[row]];
  float2 v = ((const float2*)(X + (size_t)row * 128))[lane];
  float2 f = ((const float2*)(F + (size_t)t * 128))[lane];
  float ss = v.x * v.x + v.y * v.y;
  float dp = v.x * f.x + v.y * f.y;
#pragma unroll
  for (int m = 1; m < 64; m <<= 1) {
    ss += __shfl_xor(ss, m, 64);
    dp += __shfl_xor(dp, m, 64);
  }
  float invn = 1.0f / fmaxf(sqrtf(ss), 1e-12f);
  float s = invn * K2C;               // fold 20*log2(e) into A
  ushort2 o;
  o.x = f2bf(v.x * s);
  o.y = f2bf(v.y * s);
  ((ushort2*)(Abf + (size_t)row * 128))[lane] = o;
  if (lane == 0) picked[row] = 20.0f * dp * invn;
}

// ---- convert features f32 -> bf16, zero-pad rows [100000,100352) ----
__global__ void k_conv(const float* __restrict__ F, unsigned short* __restrict__ Fbf) {
  const int NG = NPAD * 128 / 4;     // 3,211,264 groups of 4
  const int NV = NCOLS * 128 / 4;    // 3,200,000 valid groups
  int stride = gridDim.x * blockDim.x;
  for (int g = blockIdx.x * blockDim.x + threadIdx.x; g < NG; g += stride) {
    float4 v;
    if (g < NV) v = ((const float4*)F)[g];
    else        v = make_float4(0.f, 0.f, 0.f, 0.f);
    ushort4 o;
    o.x = f2bf(v.x); o.y = f2bf(v.y); o.z = f2bf(v.z); o.w = f2bf(v.w);
    ((ushort4*)Fbf)[g] = o;
  }
}

// ---- fused GEMM + sum of exp(logit - 20), fine-phase counted-vmcnt pipeline ----
// grid = 832 = 8 xcd * 104 slots; all 8 m-tiles of a chunk share one XCD.
// Ring of 4 x 16KB half-buffers (64 cols x 128 K); 3 halves in flight;
// per phase: 4 ds_read_b128 + 1 global_load_lds + 16 MFMA + 16 exp2.
__global__ __launch_bounds__(256, 2) void k_gemm(
    const unsigned short* __restrict__ Abf,
    const unsigned short* __restrict__ Fbf,
    float* __restrict__ part) {
  __shared__ unsigned short ring[4][64 * 128];    // 64 KB ring
  __shared__ float xpose[4][64];                  // part-store transpose
  const int tid = threadIdx.x;
  const int wid = tid >> 6, lane = tid & 63;
  const int lrow = lane & 15, lk = lane >> 4;

  const int slot = blockIdx.x >> 3;     // [0,104)
  const int xcd  = blockIdx.x & 7;
  const int mtile = slot & 7;
  const int chunk = (slot >> 3) * 8 + xcd;
  if (chunk >= NCHUNK) return;
  const int row0 = mtile * 256 + wid * 64;

  // A fragments in registers (Abf already scaled by 20*log2e): 64 VGPR
  short8 af[4][4];
#pragma unroll
  for (int mf = 0; mf < 4; ++mf)
#pragma unroll
    for (int ks = 0; ks < 4; ++ks)
      af[mf][ks] = *(const short8*)(Abf + (size_t)(row0 + mf * 16 + lrow) * 128 + (ks * 4 + lk) * 8);

  float racc[4][4];
#pragma unroll
  for (int mf = 0; mf < 4; ++mf)
#pragma unroll
    for (int j = 0; j < 4; ++j) racc[mf][j] = 0.f;

  const int nbase = chunk * 1024;

  // one global_load_lds (16B/thread) for half h, quarter it
  auto issue1 = [&](int h, int it) {
    int off16 = it * 256 + tid;
    int nloc = off16 >> 4, ps = off16 & 15;
    int ls = ps ^ (nloc & 7);
    const unsigned short* src = Fbf + (size_t)(nbase + h * 64 + nloc) * 128 + ls * 8;
    __builtin_amdgcn_global_load_lds((const AS1 void*)src,
                                     (AS3 void*)(&ring[h & 3][off16 * 8]), 16, 0, 0);
  };

  // 4 phases of one half-tile; stage half h+3 one quarter per phase
  auto half_body = [&](int h, bool doStage) {
    const unsigned short* sb = &ring[h & 3][0];
#pragma unroll
    for (int j = 0; j < 4; ++j) {
      short8 bfr[4];
#pragma unroll
      for (int ks = 0; ks < 4; ++ks) {
        int nloc = j * 16 + lrow;
        int phys = (ks * 4 + lk) ^ (nloc & 7);
        bfr[ks] = *(const short8*)(sb + nloc * 128 + phys * 8);
      }
      if (doStage) issue1(h + 3, j);
      __builtin_amdgcn_s_barrier();
      asm volatile("s_waitcnt lgkmcnt(0)" ::: "memory");
      __builtin_amdgcn_sched_barrier(0);
      f32x4 acc[4];
#pragma unroll
      for (int mf = 0; mf < 4; ++mf)
        acc[mf] = (f32x4){-K2C, -K2C, -K2C, -K2C};   // fold the -20 shift
      __builtin_amdgcn_s_setprio(1);
#pragma unroll
      for (int ks = 0; ks < 4; ++ks)
#pragma unroll
        for (int mf = 0; mf < 4; ++mf)
          acc[mf] = __builtin_amdgcn_mfma_f32_16x16x32_bf16(
              af[mf][ks], bfr[ks], acc[mf], 0, 0, 0);
      __builtin_amdgcn_s_setprio(0);
      // acc holds (20*cos - 20)*log2e: one exp2 per logit
#pragma unroll
      for (int mf = 0; mf < 4; ++mf)
#pragma unroll
        for (int jj = 0; jj < 4; ++jj)
          racc[mf][jj] += __builtin_amdgcn_exp2f(acc[mf][jj]);
      __builtin_amdgcn_s_barrier();
    }
  };

  // prologue: 3 halves in flight (12 loads/thread)
#pragma unroll
  for (int h = 0; h < 3; ++h)
#pragma unroll
    for (int it = 0; it < 4; ++it) issue1(h, it);

#pragma unroll 1
  for (int h = 0; h < 14; ++h) {
    // retire half h's loads (keep 8 = halves h+1,h+2 in flight), then make
    // visible to all waves before any ds_read
    asm volatile("s_waitcnt vmcnt(8)" ::: "memory");
    __builtin_amdgcn_s_barrier();
    half_body(h, h < 13);
  }
  asm volatile("s_waitcnt vmcnt(4)" ::: "memory");
  __builtin_amdgcn_s_barrier();
  half_body(14, false);
  asm volatile("s_waitcnt vmcnt(0)" ::: "memory");
  __builtin_amdgcn_s_barrier();
  half_body(15, false);

  // reduce across 16 lanes per row, transpose via LDS, coalesced store
#pragma unroll
  for (int mf = 0; mf < 4; ++mf)
#pragma unroll
    for (int j = 0; j < 4; ++j) {
      float v = racc[mf][j];
      v += __shfl_xor(v, 1, 64);
      v += __shfl_xor(v, 2, 64);
      v += __shfl_xor(v, 4, 64);
      v += __shfl_xor(v, 8, 64);
      if (lrow == 0) xpose[wid][mf * 16 + lk * 4 + j] = v;
    }
  __syncthreads();
  part[(size_t)chunk * NROWS + row0 + lane] = xpose[wid][lane];
}

// ---- stage 1 reduction: 56 blocks, each sums 14 chunks for 256 rows ----
__global__ void k_loss1(const float* __restrict__ part, float* __restrict__ psum) {
  int rb = blockIdx.x & 7, cb = blockIdx.x >> 3;   // cb in [0,7)
  int b = rb * 256 + threadIdx.x;
  float s = 0.f;
#pragma unroll
  for (int k = 0; k < 14; ++k)
    s += part[(size_t)(cb * 14 + k) * NROWS + b];
  psum[(size_t)cb * NROWS + b] = s;
}

// ---- final: per-row logz - picked, mean ----
__global__ void k_final(const float* __restrict__ psum, const float* __restrict__ picked,
                        float* __restrict__ out) {
  int tid = threadIdx.x;
  float lb = 0.f;
#pragma unroll
  for (int rr = 0; rr < 2; ++rr) {
    int b = rr * 1024 + tid;
    float tot = 0.f;
#pragma unroll
    for (int cb = 0; cb < 7; ++cb) tot += psum[(size_t)cb * NROWS + b];
    tot -= PADC;                     // remove pad-column contribution
    lb += 20.0f + logf(tot) - picked[b];
  }
#pragma unroll
  for (int m = 1; m < 64; m <<= 1) lb += __shfl_xor(lb, m, 64);
  __shared__ float red[16];
  if ((tid & 63) == 0) red[tid >> 6] = lb;
  __syncthreads();
  if (tid == 0) {
    float s = 0.f;
#pragma unroll
    for (int i = 0; i < 16; ++i) s += red[i];
    out[0] = s * (1.0f / 2048.0f);
  }
}

extern "C" void kernel_launch(void* const* d_in, const int* in_sizes, int n_in,
                              void* d_out, int out_size, void* d_ws, size_t ws_size,
                              hipStream_t stream) {
  const float* inputs  = (const float*)d_in[0];
  const int*   indexes = (const int*)d_in[1];
  const int*   labels  = (const int*)d_in[2];
  const float* feats   = (const float*)d_in[3];
  float* out = (float*)d_out;

  char* ws = (char*)d_ws;
  unsigned short* Abf = (unsigned short*)(ws + 0);        // 524,288 B
  unsigned short* Fbf = (unsigned short*)(ws + 524288);   // 25,690,112 B
  float* part   = (float*)(ws + 26214400);                // 98*2048*4 = 802,816
  float* psum   = (float*)(ws + 27017216);                // 7*2048*4  = 57,344
  float* picked = (float*)(ws + 27074560);                // 2048*4

  hipLaunchKernelGGL(k_prep,  dim3(512),  dim3(256),  0, stream, inputs, indexes, labels, feats, Abf, picked);
  hipLaunchKernelGGL(k_conv,  dim3(2048), dim3(256),  0, stream, feats, Fbf);
  hipLaunchKernelGGL(k_gemm,  dim3(832),  dim3(256),  0, stream, Abf, Fbf, part);
  hipLaunchKernelGGL(k_loss1, dim3(56),   dim3(256),  0, stream, part, psum);
  hipLaunchKernelGGL(k_final, dim3(1),    dim3(1024), 0, stream, psum, picked, out);
}

// Round 9
// 91.400 us; speedup vs baseline: 1.6299x; 1.0245x over previous
//
#include <hip/hip_runtime.h>

typedef short short8 __attribute__((ext_vector_type(8)));
typedef float f32x4 __attribute__((ext_vector_type(4)));

#define AS1 __attribute__((address_space(1)))
#define AS3 __attribute__((address_space(3)))

#define NROWS 2048
#define NCOLS 100000
#define NPAD  100352              // 98 chunks * 1024
#define NCHUNK 98
#define K2C  28.853900817779268f  // 20 * log2(e)
#define PADC 7.2552607e-7f        // 352 * exp(-20): pad-column bias

__device__ __forceinline__ unsigned short f2bf(float f) {
  unsigned int u = __float_as_uint(f);
  u = u + 0x7FFFu + ((u >> 16) & 1u);   // round to nearest even
  return (unsigned short)(u >> 16);
}

// ---- normalize inputs, scale by K2C, convert to bf16; also compute picked ----
__global__ void k_prep(const float* __restrict__ X, const int* __restrict__ idx,
                       const int* __restrict__ lab, const float* __restrict__ F,
                       unsigned short* __restrict__ Abf, float* __restrict__ picked) {
  int wid = threadIdx.x >> 6, lane = threadIdx.x & 63;
  int row = blockIdx.x * 4 + wid;
  int t = lab[idx[row]];
  float2 v = ((const float2*)(X + (size_t)row * 128))[lane];
  float2 f = ((const float2*)(F + (size_t)t * 128))[lane];
  float ss = v.x * v.x + v.y * v.y;
  float dp = v.x * f.x + v.y * f.y;
#pragma unroll
  for (int m = 1; m < 64; m <<= 1) {
    ss += __shfl_xor(ss, m, 64);
    dp += __shfl_xor(dp, m, 64);
  }
  float invn = 1.0f / fmaxf(sqrtf(ss), 1e-12f);
  float s = invn * K2C;               // fold 20*log2(e) into A
  ushort2 o;
  o.x = f2bf(v.x * s);
  o.y = f2bf(v.y * s);
  ((ushort2*)(Abf + (size_t)row * 128))[lane] = o;
  if (lane == 0) picked[row] = 20.0f * dp * invn;
}

// ---- convert features f32 -> bf16, zero-pad rows [100000,100352) ----
__global__ void k_conv(const float* __restrict__ F, unsigned short* __restrict__ Fbf) {
  const int NG = NPAD * 128 / 4;     // 3,211,264 groups of 4
  const int NV = NCOLS * 128 / 4;    // 3,200,000 valid groups
  int stride = gridDim.x * blockDim.x;
  for (int g = blockIdx.x * blockDim.x + threadIdx.x; g < NG; g += stride) {
    float4 v;
    if (g < NV) v = ((const float4*)F)[g];
    else        v = make_float4(0.f, 0.f, 0.f, 0.f);
    ushort4 o;
    o.x = f2bf(v.x); o.y = f2bf(v.y); o.z = f2bf(v.z); o.w = f2bf(v.w);
    ((ushort4*)Fbf)[g] = o;
  }
}

// ---- fused GEMM + sum of exp(logit - 20), free-flow halves ----
// grid = 832 = 8 xcd * 104 slots; all 8 m-tiles of a chunk share one XCD.
// Ring of 4 x 16KB half-buffers; 3 halves in flight via counted vmcnt(8).
// ONE barrier per half; the 4 phases inside a half flow with no sync so
// MFMA / exp2(trans) / ds_read overlap across waves.
__global__ __launch_bounds__(256, 2) void k_gemm(
    const unsigned short* __restrict__ Abf,
    const unsigned short* __restrict__ Fbf,
    float* __restrict__ part) {
  __shared__ unsigned short ring[4][64 * 128];    // 64 KB ring
  __shared__ float xpose[4][64];                  // part-store transpose
  const int tid = threadIdx.x;
  const int wid = tid >> 6, lane = tid & 63;
  const int lrow = lane & 15, lk = lane >> 4;

  const int slot = blockIdx.x >> 3;     // [0,104)
  const int xcd  = blockIdx.x & 7;
  const int mtile = slot & 7;
  const int chunk = (slot >> 3) * 8 + xcd;
  if (chunk >= NCHUNK) return;
  const int row0 = mtile * 256 + wid * 64;

  // A fragments in registers (Abf already scaled by 20*log2e): 64 VGPR
  short8 af[4][4];
#pragma unroll
  for (int mf = 0; mf < 4; ++mf)
#pragma unroll
    for (int ks = 0; ks < 4; ++ks)
      af[mf][ks] = *(const short8*)(Abf + (size_t)(row0 + mf * 16 + lrow) * 128 + (ks * 4 + lk) * 8);

  float racc[4][4];
#pragma unroll
  for (int mf = 0; mf < 4; ++mf)
#pragma unroll
    for (int j = 0; j < 4; ++j) racc[mf][j] = 0.f;

  const int nbase = chunk * 1024;

  // one global_load_lds (16B/thread) for half h, quarter it
  auto issue1 = [&](int h, int it) {
    int off16 = it * 256 + tid;
    int nloc = off16 >> 4, ps = off16 & 15;
    int ls = ps ^ (nloc & 7);
    const unsigned short* src = Fbf + (size_t)(nbase + h * 64 + nloc) * 128 + ls * 8;
    __builtin_amdgcn_global_load_lds((const AS1 void*)src,
                                     (AS3 void*)(&ring[h & 3][off16 * 8]), 16, 0, 0);
  };

  // 4 phases of one half-tile, NO internal barriers; stage h+3 1 qtr/phase
  auto half_body = [&](int h, bool doStage) {
    const unsigned short* sb = &ring[h & 3][0];
#pragma unroll
    for (int j = 0; j < 4; ++j) {
      short8 bfr[4];
#pragma unroll
      for (int ks = 0; ks < 4; ++ks) {
        int nloc = j * 16 + lrow;
        int phys = (ks * 4 + lk) ^ (nloc & 7);
        bfr[ks] = *(const short8*)(sb + nloc * 128 + phys * 8);
      }
      if (doStage) issue1(h + 3, j);
      f32x4 acc[4];
#pragma unroll
      for (int mf = 0; mf < 4; ++mf)
        acc[mf] = (f32x4){-K2C, -K2C, -K2C, -K2C};   // fold the -20 shift
      __builtin_amdgcn_s_setprio(1);
#pragma unroll
      for (int ks = 0; ks < 4; ++ks)
#pragma unroll
        for (int mf = 0; mf < 4; ++mf)
          acc[mf] = __builtin_amdgcn_mfma_f32_16x16x32_bf16(
              af[mf][ks], bfr[ks], acc[mf], 0, 0, 0);
      __builtin_amdgcn_s_setprio(0);
      // acc holds (20*cos - 20)*log2e: one exp2 per logit
#pragma unroll
      for (int mf = 0; mf < 4; ++mf)
#pragma unroll
        for (int jj = 0; jj < 4; ++jj)
          racc[mf][jj] += __builtin_amdgcn_exp2f(acc[mf][jj]);
    }
  };

  // prologue: 3 halves in flight (12 loads/thread)
#pragma unroll
  for (int h = 0; h < 3; ++h)
#pragma unroll
    for (int it = 0; it < 4; ++it) issue1(h, it);

#pragma unroll 1
  for (int h = 0; h < 14; ++h) {
    // retire half h's loads (keep h+1,h+2 in flight); barrier doubles as
    // cross-wave visibility AND ring-slot (h+3 == h-1 mod 4) protection
    asm volatile("s_waitcnt vmcnt(8)" ::: "memory");
    __builtin_amdgcn_s_barrier();
    half_body(h, h < 13);
  }
  asm volatile("s_waitcnt vmcnt(4)" ::: "memory");
  __builtin_amdgcn_s_barrier();
  half_body(14, false);
  asm volatile("s_waitcnt vmcnt(0)" ::: "memory");
  __builtin_amdgcn_s_barrier();
  half_body(15, false);

  // reduce across 16 lanes per row, transpose via LDS, coalesced store
#pragma unroll
  for (int mf = 0; mf < 4; ++mf)
#pragma unroll
    for (int j = 0; j < 4; ++j) {
      float v = racc[mf][j];
      v += __shfl_xor(v, 1, 64);
      v += __shfl_xor(v, 2, 64);
      v += __shfl_xor(v, 4, 64);
      v += __shfl_xor(v, 8, 64);
      if (lrow == 0) xpose[wid][mf * 16 + lk * 4 + j] = v;
    }
  __syncthreads();
  part[(size_t)chunk * NROWS + row0 + lane] = xpose[wid][lane];
}

// ---- stage 1 reduction: 56 blocks, each sums 14 chunks for 256 rows ----
__global__ void k_loss1(const float* __restrict__ part, float* __restrict__ psum) {
  int rb = blockIdx.x & 7, cb = blockIdx.x >> 3;   // cb in [0,7)
  int b = rb * 256 + threadIdx.x;
  float s = 0.f;
#pragma unroll
  for (int k = 0; k < 14; ++k)
    s += part[(size_t)(cb * 14 + k) * NROWS + b];
  psum[(size_t)cb * NROWS + b] = s;
}

// ---- final: per-row logz - picked, mean ----
__global__ void k_final(const float* __restrict__ psum, const float* __restrict__ picked,
                        float* __restrict__ out) {
  int tid = threadIdx.x;
  float lb = 0.f;
#pragma unroll
  for (int rr = 0; rr < 2; ++rr) {
    int b = rr * 1024 + tid;
    float tot = 0.f;
#pragma unroll
    for (int cb = 0; cb < 7; ++cb) tot += psum[(size_t)cb * NROWS + b];
    tot -= PADC;                     // remove pad-column contribution
    lb += 20.0f + logf(tot) - picked[b];
  }
#pragma unroll
  for (int m = 1; m < 64; m <<= 1) lb += __shfl_xor(lb, m, 64);
  __shared__ float red[16];
  if ((tid & 63) == 0) red[tid >> 6] = lb;
  __syncthreads();
  if (tid == 0) {
    float s = 0.f;
#pragma unroll
    for (int i = 0; i < 16; ++i) s += red[i];
    out[0] = s * (1.0f / 2048.0f);
  }
}

extern "C" void kernel_launch(void* const* d_in, const int* in_sizes, int n_in,
                              void* d_out, int out_size, void* d_ws, size_t ws_size,
                              hipStream_t stream) {
  const float* inputs  = (const float*)d_in[0];
  const int*   indexes = (const int*)d_in[1];
  const int*   labels  = (const int*)d_in[2];
  const float* feats   = (const float*)d_in[3];
  float* out = (float*)d_out;

  char* ws = (char*)d_ws;
  unsigned short* Abf = (unsigned short*)(ws + 0);        // 524,288 B
  unsigned short* Fbf = (unsigned short*)(ws + 524288);   // 25,690,112 B
  float* part   = (float*)(ws + 26214400);                // 98*2048*4 = 802,816
  float* psum   = (float*)(ws + 27017216);                // 7*2048*4  = 57,344
  float* picked = (float*)(ws + 27074560);                // 2048*4

  hipLaunchKernelGGL(k_prep,  dim3(512),  dim3(256),  0, stream, inputs, indexes, labels, feats, Abf, picked);
  hipLaunchKernelGGL(k_conv,  dim3(2048), dim3(256),  0, stream, feats, Fbf);
  hipLaunchKernelGGL(k_gemm,  dim3(832),  dim3(256),  0, stream, Abf, Fbf, part);
  hipLaunchKernelGGL(k_loss1, dim3(56),   dim3(256),  0, stream, part, psum);
  hipLaunchKernelGGL(k_final, dim3(1),    dim3(1024), 0, stream, psum, picked, out);
}